// Round 1
// 1276.726 us; speedup vs baseline: 1.0482x; 1.0482x over previous
//
#include <hip/hip_runtime.h>

// K-means assignment via split-fp16 MFMA GEMM + fused argmin.
// d2 = x2 + c2 - 2*x.cT ; x = hi+lo (fp16 each), dot = hh + hl + lh on
// mfma_f32_16x16x32_f16 (fp32 accum). Error ~1e-6 < fp32 sum-order noise.
// N=131072, K=2048, D=512.
//
// This revision (vs 1338us baseline):
//  - T2: XOR-swizzled LDS tiles (swizzle carried by pre-swizzled GLOBAL source
//    since global_load_lds writes linearly); fragment ds_read_b128 goes from
//    8-way bank conflict (6.7e7 conflict cycles/dispatch) to 2-way (free).
//  - minimum 2-phase pipeline: double-buffered LDS, stage(t+1) issued BEFORE
//    compute(t), ONE __syncthreads per K-step (down from 2) so the
//    global_load_lds latency drains under the MFMA cluster.
//  - s_setprio(1) around the MFMA cluster (2 independent blocks/CU -> role
//    diversity exists for the scheduler to arbitrate).

#define N_PTS 131072
#define K_CL  2048
#define D_DIM 512
#define BM 128
#define BN 128
#define BK 32
#define NKT (K_CL / BN)    // 16 K-tiles
#define NDT (D_DIM / BK)   // 16 D-steps
#define NT  (NKT * NDT)    // 256 total iterations

typedef _Float16 half8  __attribute__((ext_vector_type(8)));
typedef _Float16 half4v __attribute__((ext_vector_type(4)));
typedef float    floatx4 __attribute__((ext_vector_type(4)));

// async global->LDS, 16B per lane; LDS dest = wave-uniform base + lane*16,
// global source address is PER-LANE (carries the swizzle).
#define GLL(g, l) __builtin_amdgcn_global_load_lds( \
    (__attribute__((address_space(1))) void*)(g),   \
    (__attribute__((address_space(3))) void*)(l), 16, 0, 0)

// ---- c2 norms: one wave per row (identical numerics to round-1 pass) ----
__global__ void row_norms_kernel(const float* __restrict__ A,
                                 float* __restrict__ out, int rows) {
    int gid  = blockIdx.x * blockDim.x + threadIdx.x;
    int wave = gid >> 6;
    int lane = gid & 63;
    if (wave >= rows) return;
    const float4* a = (const float4*)(A + (size_t)wave * D_DIM);
    float4 p = a[lane];
    float4 q = a[lane + 64];
    float s = p.x*p.x + p.y*p.y + p.z*p.z + p.w*p.w
            + q.x*q.x + q.y*q.y + q.z*q.z + q.w*q.w;
    #pragma unroll
    for (int off = 32; off > 0; off >>= 1) s += __shfl_down(s, off, 64);
    if (lane == 0) out[wave] = s;
}

// ---- fp32 -> (hi,lo) fp16 planes ----
__global__ void conv_f16x2_kernel(const float* __restrict__ src,
                                  _Float16* __restrict__ hi,
                                  _Float16* __restrict__ lo, int n4) {
    int i = blockIdx.x * blockDim.x + threadIdx.x;
    if (i >= n4) return;
    float4 v = ((const float4*)src)[i];
    half4v h, l;
    h.x = (_Float16)v.x; h.y = (_Float16)v.y;
    h.z = (_Float16)v.z; h.w = (_Float16)v.w;
    l.x = (_Float16)(v.x - (float)h.x);
    l.y = (_Float16)(v.y - (float)h.y);
    l.z = (_Float16)(v.z - (float)h.z);
    l.w = (_Float16)(v.w - (float)h.w);
    *(half4v*)(hi + (size_t)i * 4) = h;
    *(half4v*)(lo + (size_t)i * 4) = l;
}

// ---- main: 128x128 block over all K, split-fp16 MFMA, fused argmin ----
// LDS tile swizzle: logical element [row][k], 16B chunk j = k/8 (0..3),
// stored at chunk position j ^ ((row>>1)&3). Staging pre-swizzles the
// GLOBAL source chunk; reads use swizzled chunk. Fragment ds_read_b128 at
// granule (row*4 + (q^((row>>1)&3))) mod 8 covers all 8 granules twice per
// 16-lane group => 2-way (free) instead of 8-way.
template<bool XPRE, bool CPRE>
__global__ __launch_bounds__(256, 2)
void kmeans_mfma(const float* __restrict__ X, const float* __restrict__ C,
                 const _Float16* __restrict__ Xhi, const _Float16* __restrict__ Xlo,
                 const _Float16* __restrict__ Chi, const _Float16* __restrict__ Clo,
                 const float* __restrict__ c2g, int* __restrict__ out) {
    // double-buffered unpadded [row][BK] f16 tiles (64B rows; linear dest
    // required by global_load_lds)
    __shared__ __align__(16) _Float16 sXh[2][BM * BK], sXl[2][BM * BK];
    __shared__ __align__(16) _Float16 sCh[2][BN * BK], sCl[2][BN * BK];
    __shared__ float c2s[K_CL];      // 8 KB
    __shared__ float x2s[BM];

    const int tid  = threadIdx.x;
    const int lane = tid & 63;
    const int w    = tid >> 6;       // wave id 0..3
    const int wti  = w >> 1;         // row half
    const int wtj  = w & 1;          // col half
    const int q    = lane >> 4;      // quad
    const int m16  = lane & 15;
    const int rowBase = blockIdx.x * BM;

    // swizzle constants (halves offsets)
    const int jsrc = (((lane & 3) ^ ((lane >> 3) & 3)) * 8);  // staging: src chunk for lane
    const int swq8 = ((q ^ ((m16 >> 1) & 3)) * 8);            // read: chunk position of logical chunk q

    // c2 into LDS
    if (CPRE) {
        for (int i = tid; i < K_CL / 4; i += 256)
            ((float4*)c2s)[i] = ((const float4*)c2g)[i];
    } else {
        for (int k = tid; k < K_CL; k += 256) {
            const float4* cp = (const float4*)(C + (size_t)k * D_DIM);
            float s0 = 0.f, s1 = 0.f;
            for (int j = 0; j < D_DIM / 4; j += 2) {
                float4 a = cp[j], b = cp[j + 1];
                s0 += a.x*a.x + a.y*a.y + a.z*a.z + a.w*a.w;
                s1 += b.x*b.x + b.y*b.y + b.z*b.z + b.w*b.w;
            }
            c2s[k] = s0 + s1;
        }
    }
    // x2 into LDS (2 threads per row; partials staged in sXh scratch)
    {
        int r = tid & 127, h = tid >> 7;
        const float4* xp = (const float4*)(X + (size_t)(rowBase + r) * D_DIM + h * 256);
        float s0 = 0.f, s1 = 0.f;
        for (int j = 0; j < 64; j += 2) {
            float4 a = xp[j], b = xp[j + 1];
            s0 += a.x*a.x + a.y*a.y + a.z*a.z + a.w*a.w;
            s1 += b.x*b.x + b.y*b.y + b.z*b.z + b.w*b.w;
        }
        ((float*)sXh)[tid] = s0 + s1;
    }
    __syncthreads();
    if (tid < BM) x2s[tid] = ((float*)sXh)[tid] + ((float*)sXh)[tid + 128];
    __syncthreads();   // scratch reads done before staging overwrites buf0

    // on-the-fly staging mapping (fallback paths)
    const int s_c4 = tid & 7;    // float4-col within BK
    const int s_r0 = tid >> 3;   // row 0..31

    // stage tile t (t = kt*NDT + dt) into buffer t&1
    auto stage = [&](int t) {
        const int dtl = t & (NDT - 1);
        const int ktl = t >> 4;              // NDT == 16
        const int d0  = dtl * BK;
        const int k0l = ktl * BN;
        const int b   = t & 1;
        _Float16* dXh = sXh[b]; _Float16* dXl = sXl[b];
        _Float16* dCh = sCh[b]; _Float16* dCl = sCl[b];
        if constexpr (XPRE) {
            #pragma unroll
            for (int s = 0; s < 2; ++s) {
                const int cc = w * 2 + s;                // 16-row chunk
                const int r  = cc * 16 + (lane >> 2);
                const size_t go = (size_t)(rowBase + r) * D_DIM + d0 + jsrc;
                GLL(Xhi + go, &dXh[cc * 512]);
                GLL(Xlo + go, &dXl[cc * 512]);
            }
        } else {
            #pragma unroll
            for (int p = 0; p < 4; ++p) {
                const int r = s_r0 + p * 32;
                float4 v = *(const float4*)&X[(size_t)(rowBase + r) * D_DIM + d0 + s_c4 * 4];
                half4v h, l;
                h.x = (_Float16)v.x; h.y = (_Float16)v.y;
                h.z = (_Float16)v.z; h.w = (_Float16)v.w;
                l.x = (_Float16)(v.x - (float)h.x);
                l.y = (_Float16)(v.y - (float)h.y);
                l.z = (_Float16)(v.z - (float)h.z);
                l.w = (_Float16)(v.w - (float)h.w);
                const int off = r * BK + (((s_c4 >> 1) ^ ((r >> 1) & 3)) * 8) + (s_c4 & 1) * 4;
                *(half4v*)&dXh[off] = h;
                *(half4v*)&dXl[off] = l;
            }
        }
        if constexpr (CPRE) {
            #pragma unroll
            for (int s = 0; s < 2; ++s) {
                const int cc = w * 2 + s;
                const int r  = cc * 16 + (lane >> 2);
                const size_t go = (size_t)(k0l + r) * D_DIM + d0 + jsrc;
                GLL(Chi + go, &dCh[cc * 512]);
                GLL(Clo + go, &dCl[cc * 512]);
            }
        } else {
            #pragma unroll
            for (int p = 0; p < 4; ++p) {
                const int r = s_r0 + p * 32;
                float4 v = *(const float4*)&C[(size_t)(k0l + r) * D_DIM + d0 + s_c4 * 4];
                half4v h, l;
                h.x = (_Float16)v.x; h.y = (_Float16)v.y;
                h.z = (_Float16)v.z; h.w = (_Float16)v.w;
                l.x = (_Float16)(v.x - (float)h.x);
                l.y = (_Float16)(v.y - (float)h.y);
                l.z = (_Float16)(v.z - (float)h.z);
                l.w = (_Float16)(v.w - (float)h.w);
                const int off = r * BK + (((s_c4 >> 1) ^ ((r >> 1) & 3)) * 8) + (s_c4 & 1) * 4;
                *(half4v*)&dCh[off] = h;
                *(half4v*)&dCl[off] = l;
            }
        }
    };

    float bestV[4][4];
    int   bestI[4][4];
    #pragma unroll
    for (int ti = 0; ti < 4; ++ti)
        #pragma unroll
        for (int r = 0; r < 4; ++r) { bestV[ti][r] = 3.4e38f; bestI[ti][r] = 0; }

    // prologue: stage tile 0, drain
    stage(0);
    __syncthreads();

    #pragma unroll 1
    for (int kt = 0; kt < NKT; ++kt) {
        const int k0 = kt * BN;
        floatx4 acc[4][4];
        #pragma unroll
        for (int ti = 0; ti < 4; ++ti)
            #pragma unroll
            for (int tj = 0; tj < 4; ++tj) acc[ti][tj] = (floatx4){0.f, 0.f, 0.f, 0.f};

        #pragma unroll 2
        for (int dt = 0; dt < NDT; ++dt) {
            const int t = kt * NDT + dt;
            // prefetch next tile into the other buffer (its readers finished
            // before the barrier that ended iteration t-1)
            if (t + 1 < NT) stage(t + 1);

            const int b = t & 1;
            const _Float16* bXh = sXh[b]; const _Float16* bXl = sXl[b];
            const _Float16* bCh = sCh[b]; const _Float16* bCl = sCl[b];

            // A fragments: A[m=lane&15][k=quad*8+j], swizzled chunk position
            half8 ah[4], al[4];
            #pragma unroll
            for (int ti = 0; ti < 4; ++ti) {
                const int row = wti * 64 + ti * 16 + m16;
                ah[ti] = *(const half8*)&bXh[row * BK + swq8];
                al[ti] = *(const half8*)&bXl[row * BK + swq8];
            }
            __builtin_amdgcn_s_setprio(1);
            #pragma unroll
            for (int tj = 0; tj < 4; ++tj) {
                const int col = wtj * 64 + tj * 16 + m16;
                half8 bh = *(const half8*)&bCh[col * BK + swq8];
                half8 bl = *(const half8*)&bCl[col * BK + swq8];
                #pragma unroll
                for (int ti = 0; ti < 4; ++ti) {
                    floatx4 a = acc[ti][tj];
                    a = __builtin_amdgcn_mfma_f32_16x16x32_f16(ah[ti], bh, a, 0, 0, 0);
                    a = __builtin_amdgcn_mfma_f32_16x16x32_f16(ah[ti], bl, a, 0, 0, 0);
                    a = __builtin_amdgcn_mfma_f32_16x16x32_f16(al[ti], bh, a, 0, 0, 0);
                    acc[ti][tj] = a;
                }
            }
            __builtin_amdgcn_s_setprio(0);
            // single barrier per K-step: drains this iteration's prefetch
            // (vmcnt) and orders reads of buf[b] before next-iter overwrite
            __syncthreads();
        }

        // fused argmin epilogue. D layout: col=lane&15, row=quad*4+reg.
        // cols ascend (kt, then tj) per (ti,reg) + strict '<'  => first-occurrence.
        #pragma unroll
        for (int tj = 0; tj < 4; ++tj) {
            int col = k0 + wtj * 64 + tj * 16 + m16;
            float cv = c2s[col];
            #pragma unroll
            for (int ti = 0; ti < 4; ++ti)
                #pragma unroll
                for (int r = 0; r < 4; ++r) {
                    float s = x2s[wti * 64 + ti * 16 + q * 4 + r] + cv;
                    float v = s - 2.0f * acc[ti][tj][r];
                    if (v < bestV[ti][r]) { bestV[ti][r] = v; bestI[ti][r] = col; }
                }
        }
    }

    // cross-lane reduce over the 16 lanes sharing each row (lexicographic)
    #pragma unroll
    for (int ti = 0; ti < 4; ++ti)
        #pragma unroll
        for (int r = 0; r < 4; ++r) {
            float v = bestV[ti][r]; int ix = bestI[ti][r];
            #pragma unroll
            for (int off = 1; off < 16; off <<= 1) {
                float ov = __shfl_xor(v, off, 64);
                int   oi = __shfl_xor(ix, off, 64);
                if (ov < v || (ov == v && oi < ix)) { v = ov; ix = oi; }
            }
            bestV[ti][r] = v; bestI[ti][r] = ix;
        }

    __syncthreads();                   // tiles no longer needed; reuse as scratch
    float* rv  = (float*)sXh;          // [128][2]
    int*   rix = (int*)sCh;            // [128][2]
    if (m16 == 0) {
        #pragma unroll
        for (int ti = 0; ti < 4; ++ti)
            #pragma unroll
            for (int r = 0; r < 4; ++r) {
                int rloc = wti * 64 + ti * 16 + q * 4 + r;
                rv[rloc * 2 + wtj]  = bestV[ti][r];
                rix[rloc * 2 + wtj] = bestI[ti][r];
            }
    }
    __syncthreads();
    if (tid < BM) {
        float v0 = rv[tid * 2], v1 = rv[tid * 2 + 1];
        int   i0 = rix[tid * 2], i1 = rix[tid * 2 + 1];
        out[rowBase + tid] = (v1 < v0 || (v1 == v0 && i1 < i0)) ? i1 : i0;
    }
}

extern "C" void kernel_launch(void* const* d_in, const int* in_sizes, int n_in,
                              void* d_out, int out_size, void* d_ws, size_t ws_size,
                              hipStream_t stream) {
    const float* X = (const float*)d_in[0];   // [N, D]
    const float* C = (const float*)d_in[1];   // [K, D]
    int* out = (int*)d_out;

    char* ws = (char*)d_ws;
    const size_t c2_off  = 0;
    const size_t chi_off = (size_t)K_CL * 4;                       // 8 KB
    const size_t clo_off = chi_off + (size_t)K_CL * D_DIM * 2;     // +2 MB
    const size_t xhi_off = clo_off + (size_t)K_CL * D_DIM * 2;     // +2 MB
    const size_t xlo_off = xhi_off + (size_t)N_PTS * D_DIM * 2;    // +128 MB
    const size_t need_C    = xhi_off;                              // ~4.2 MB
    const size_t need_full = xlo_off + (size_t)N_PTS * D_DIM * 2;  // ~272.6 MB

    if (ws_size >= need_full) {
        float*    c2  = (float*)(ws + c2_off);
        _Float16* Chi = (_Float16*)(ws + chi_off);
        _Float16* Clo = (_Float16*)(ws + clo_off);
        _Float16* Xhi = (_Float16*)(ws + xhi_off);
        _Float16* Xlo = (_Float16*)(ws + xlo_off);
        row_norms_kernel<<<(K_CL * 64) / 256, 256, 0, stream>>>(C, c2, K_CL);
        conv_f16x2_kernel<<<(K_CL * D_DIM / 4) / 256, 256, 0, stream>>>(
            C, Chi, Clo, K_CL * D_DIM / 4);
        conv_f16x2_kernel<<<(N_PTS * D_DIM / 4 + 255) / 256, 256, 0, stream>>>(
            X, Xhi, Xlo, N_PTS * D_DIM / 4);
        kmeans_mfma<true, true><<<N_PTS / BM, 256, 0, stream>>>(
            X, C, Xhi, Xlo, Chi, Clo, c2, out);
    } else if (ws_size >= need_C) {
        float*    c2  = (float*)(ws + c2_off);
        _Float16* Chi = (_Float16*)(ws + chi_off);
        _Float16* Clo = (_Float16*)(ws + clo_off);
        row_norms_kernel<<<(K_CL * 64) / 256, 256, 0, stream>>>(C, c2, K_CL);
        conv_f16x2_kernel<<<(K_CL * D_DIM / 4) / 256, 256, 0, stream>>>(
            C, Chi, Clo, K_CL * D_DIM / 4);
        kmeans_mfma<false, true><<<N_PTS / BM, 256, 0, stream>>>(
            X, C, nullptr, nullptr, Chi, Clo, c2, out);
    } else {
        kmeans_mfma<false, false><<<N_PTS / BM, 256, 0, stream>>>(
            X, C, nullptr, nullptr, nullptr, nullptr, nullptr, out);
    }
}

// Round 2
// 1214.547 us; speedup vs baseline: 1.1018x; 1.0512x over previous
//
#include <hip/hip_runtime.h>

// K-means assignment via split-fp16 MFMA GEMM + fused argmin.
// d2 = x2 + c2 - 2*x.cT ; x = hi+lo (fp16 each), dot = hh + hl + lh on
// mfma_f32_16x16x32_f16 (fp32 accum). Error ~1e-6 < fp32 sum-order noise.
// N=131072, K=2048, D=512.
//
// R2 (vs 957us main kernel): T4 counted-vmcnt split-barrier pipeline.
//   iter t: {ds_read 16 frags -> lgkmcnt(0)+barrier1 -> stage(t+2) into the
//   buffer just read -> 48 MFMA -> vmcnt(8)+barrier2}. stage(t+1)'s loads
//   (needed at barrier2) were issued a FULL iteration earlier -> ~1000cy of
//   cover for ~900cy HBM latency; the wait is counted (8 = t+2's in-flight
//   GLLs), never a drain-to-0. Raw s_barrier + inline-asm waitcnt; "memory"
//   clobbers + sched_barrier(0) per rule #18. Fallback (no-ws) paths keep
//   plain __syncthreads with the same 2-buffer structure.
// Carried from R1: XOR-swizzled LDS (bank conflicts = 0), s_setprio around
// MFMA cluster, double-buffered tiles.

#define N_PTS 131072
#define K_CL  2048
#define D_DIM 512
#define BM 128
#define BN 128
#define BK 32
#define NKT (K_CL / BN)    // 16 K-tiles
#define NDT (D_DIM / BK)   // 16 D-steps
#define NT  (NKT * NDT)    // 256 total iterations

typedef _Float16 half8  __attribute__((ext_vector_type(8)));
typedef _Float16 half4v __attribute__((ext_vector_type(4)));
typedef float    floatx4 __attribute__((ext_vector_type(4)));

// async global->LDS, 16B per lane; LDS dest = wave-uniform base + lane*16,
// global source address is PER-LANE (carries the swizzle).
#define GLL(g, l) __builtin_amdgcn_global_load_lds( \
    (__attribute__((address_space(1))) void*)(g),   \
    (__attribute__((address_space(3))) void*)(l), 16, 0, 0)

// ---- c2 norms: one wave per row ----
__global__ void row_norms_kernel(const float* __restrict__ A,
                                 float* __restrict__ out, int rows) {
    int gid  = blockIdx.x * blockDim.x + threadIdx.x;
    int wave = gid >> 6;
    int lane = gid & 63;
    if (wave >= rows) return;
    const float4* a = (const float4*)(A + (size_t)wave * D_DIM);
    float4 p = a[lane];
    float4 q = a[lane + 64];
    float s = p.x*p.x + p.y*p.y + p.z*p.z + p.w*p.w
            + q.x*q.x + q.y*q.y + q.z*q.z + q.w*q.w;
    #pragma unroll
    for (int off = 32; off > 0; off >>= 1) s += __shfl_down(s, off, 64);
    if (lane == 0) out[wave] = s;
}

// ---- fp32 -> (hi,lo) fp16 planes ----
__global__ void conv_f16x2_kernel(const float* __restrict__ src,
                                  _Float16* __restrict__ hi,
                                  _Float16* __restrict__ lo, int n4) {
    int i = blockIdx.x * blockDim.x + threadIdx.x;
    if (i >= n4) return;
    float4 v = ((const float4*)src)[i];
    half4v h, l;
    h.x = (_Float16)v.x; h.y = (_Float16)v.y;
    h.z = (_Float16)v.z; h.w = (_Float16)v.w;
    l.x = (_Float16)(v.x - (float)h.x);
    l.y = (_Float16)(v.y - (float)h.y);
    l.z = (_Float16)(v.z - (float)h.z);
    l.w = (_Float16)(v.w - (float)h.w);
    *(half4v*)(hi + (size_t)i * 4) = h;
    *(half4v*)(lo + (size_t)i * 4) = l;
}

// ---- main: 128x128 block over all K, split-fp16 MFMA, fused argmin ----
// LDS tile swizzle: logical element [row][k], 16B chunk j = k/8 (0..3),
// stored at chunk position j ^ ((row>>1)&3). Staging pre-swizzles the
// GLOBAL source chunk (global_load_lds writes linearly); reads use swizzled
// chunk position. Fragment ds_read_b128 => 2-way bank access (free).
template<bool XPRE, bool CPRE>
__global__ __launch_bounds__(256, 2)
void kmeans_mfma(const float* __restrict__ X, const float* __restrict__ C,
                 const _Float16* __restrict__ Xhi, const _Float16* __restrict__ Xlo,
                 const _Float16* __restrict__ Chi, const _Float16* __restrict__ Clo,
                 const float* __restrict__ c2g, int* __restrict__ out) {
    constexpr bool ASYNC = XPRE && CPRE;   // pure global_load_lds staging

    // double-buffered unpadded [row][BK] f16 tiles (64B rows; linear dest
    // required by global_load_lds)
    __shared__ __align__(16) _Float16 sXh[2][BM * BK], sXl[2][BM * BK];
    __shared__ __align__(16) _Float16 sCh[2][BN * BK], sCl[2][BN * BK];
    __shared__ float c2s[K_CL];      // 8 KB
    __shared__ float x2s[BM];

    const int tid  = threadIdx.x;
    const int lane = tid & 63;
    const int w    = tid >> 6;       // wave id 0..3
    const int wti  = w >> 1;         // row half
    const int wtj  = w & 1;          // col half
    const int q    = lane >> 4;      // quad
    const int m16  = lane & 15;
    const int rowBase = blockIdx.x * BM;

    // swizzle constants (halves offsets)
    const int jsrc = (((lane & 3) ^ ((lane >> 3) & 3)) * 8);  // staging: src chunk for lane
    const int swq8 = ((q ^ ((m16 >> 1) & 3)) * 8);            // read: chunk position of logical chunk q

    // c2 into LDS
    if (CPRE) {
        for (int i = tid; i < K_CL / 4; i += 256)
            ((float4*)c2s)[i] = ((const float4*)c2g)[i];
    } else {
        for (int k = tid; k < K_CL; k += 256) {
            const float4* cp = (const float4*)(C + (size_t)k * D_DIM);
            float s0 = 0.f, s1 = 0.f;
            for (int j = 0; j < D_DIM / 4; j += 2) {
                float4 a = cp[j], b = cp[j + 1];
                s0 += a.x*a.x + a.y*a.y + a.z*a.z + a.w*a.w;
                s1 += b.x*b.x + b.y*b.y + b.z*b.z + b.w*b.w;
            }
            c2s[k] = s0 + s1;
        }
    }
    // x2 into LDS (2 threads per row; partials staged in sXh scratch)
    {
        int r = tid & 127, h = tid >> 7;
        const float4* xp = (const float4*)(X + (size_t)(rowBase + r) * D_DIM + h * 256);
        float s0 = 0.f, s1 = 0.f;
        for (int j = 0; j < 64; j += 2) {
            float4 a = xp[j], b = xp[j + 1];
            s0 += a.x*a.x + a.y*a.y + a.z*a.z + a.w*a.w;
            s1 += b.x*b.x + b.y*b.y + b.z*b.z + b.w*b.w;
        }
        ((float*)sXh)[tid] = s0 + s1;
    }
    __syncthreads();
    if (tid < BM) x2s[tid] = ((float*)sXh)[tid] + ((float*)sXh)[tid + 128];
    __syncthreads();   // scratch reads done before staging overwrites buf0

    // on-the-fly staging mapping (fallback paths)
    const int s_c4 = tid & 7;    // float4-col within BK
    const int s_r0 = tid >> 3;   // row 0..31

    // stage tile t (t = kt*NDT + dt) into buffer t&1
    auto stage = [&](int t) {
        const int dtl = t & (NDT - 1);
        const int ktl = t >> 4;              // NDT == 16
        const int d0  = dtl * BK;
        const int k0l = ktl * BN;
        const int b   = t & 1;
        _Float16* dXh = sXh[b]; _Float16* dXl = sXl[b];
        _Float16* dCh = sCh[b]; _Float16* dCl = sCl[b];
        if constexpr (XPRE) {
            #pragma unroll
            for (int s = 0; s < 2; ++s) {
                const int cc = w * 2 + s;                // 16-row chunk
                const int r  = cc * 16 + (lane >> 2);
                const size_t go = (size_t)(rowBase + r) * D_DIM + d0 + jsrc;
                GLL(Xhi + go, &dXh[cc * 512]);
                GLL(Xlo + go, &dXl[cc * 512]);
            }
        } else {
            #pragma unroll
            for (int p = 0; p < 4; ++p) {
                const int r = s_r0 + p * 32;
                float4 v = *(const float4*)&X[(size_t)(rowBase + r) * D_DIM + d0 + s_c4 * 4];
                half4v h, l;
                h.x = (_Float16)v.x; h.y = (_Float16)v.y;
                h.z = (_Float16)v.z; h.w = (_Float16)v.w;
                l.x = (_Float16)(v.x - (float)h.x);
                l.y = (_Float16)(v.y - (float)h.y);
                l.z = (_Float16)(v.z - (float)h.z);
                l.w = (_Float16)(v.w - (float)h.w);
                const int off = r * BK + (((s_c4 >> 1) ^ ((r >> 1) & 3)) * 8) + (s_c4 & 1) * 4;
                *(half4v*)&dXh[off] = h;
                *(half4v*)&dXl[off] = l;
            }
        }
        if constexpr (CPRE) {
            #pragma unroll
            for (int s = 0; s < 2; ++s) {
                const int cc = w * 2 + s;
                const int r  = cc * 16 + (lane >> 2);
                const size_t go = (size_t)(k0l + r) * D_DIM + d0 + jsrc;
                GLL(Chi + go, &dCh[cc * 512]);
                GLL(Clo + go, &dCl[cc * 512]);
            }
        } else {
            #pragma unroll
            for (int p = 0; p < 4; ++p) {
                const int r = s_r0 + p * 32;
                float4 v = *(const float4*)&C[(size_t)(k0l + r) * D_DIM + d0 + s_c4 * 4];
                half4v h, l;
                h.x = (_Float16)v.x; h.y = (_Float16)v.y;
                h.z = (_Float16)v.z; h.w = (_Float16)v.w;
                l.x = (_Float16)(v.x - (float)h.x);
                l.y = (_Float16)(v.y - (float)h.y);
                l.z = (_Float16)(v.z - (float)h.z);
                l.w = (_Float16)(v.w - (float)h.w);
                const int off = r * BK + (((s_c4 >> 1) ^ ((r >> 1) & 3)) * 8) + (s_c4 & 1) * 4;
                *(half4v*)&dCh[off] = h;
                *(half4v*)&dCl[off] = l;
            }
        }
    };

    float bestV[4][4];
    int   bestI[4][4];
    #pragma unroll
    for (int ti = 0; ti < 4; ++ti)
        #pragma unroll
        for (int r = 0; r < 4; ++r) { bestV[ti][r] = 3.4e38f; bestI[ti][r] = 0; }

    // prologue: stage tiles 0 and 1; need only tile 0 complete to start.
    stage(0);
    stage(1);
    if constexpr (ASYNC) {
        asm volatile("s_waitcnt vmcnt(8)" ::: "memory");  // stage(0) landed
        __builtin_amdgcn_s_barrier();
    } else {
        __syncthreads();
    }

    #pragma unroll 1
    for (int kt = 0; kt < NKT; ++kt) {
        const int k0 = kt * BN;
        floatx4 acc[4][4];
        #pragma unroll
        for (int ti = 0; ti < 4; ++ti)
            #pragma unroll
            for (int tj = 0; tj < 4; ++tj) acc[ti][tj] = (floatx4){0.f, 0.f, 0.f, 0.f};

        #pragma unroll 2
        for (int dt = 0; dt < NDT; ++dt) {
            const int t = kt * NDT + dt;
            const int b = t & 1;
            const _Float16* bXh = sXh[b]; const _Float16* bXl = sXl[b];
            const _Float16* bCh = sCh[b]; const _Float16* bCl = sCl[b];

            // ALL fragments -> regs upfront (frees the buffer for overwrite)
            half8 ah[4], al[4], bh[4], bl[4];
            #pragma unroll
            for (int ti = 0; ti < 4; ++ti) {
                const int row = wti * 64 + ti * 16 + m16;
                ah[ti] = *(const half8*)&bXh[row * BK + swq8];
                al[ti] = *(const half8*)&bXl[row * BK + swq8];
            }
            #pragma unroll
            for (int tj = 0; tj < 4; ++tj) {
                const int col = wtj * 64 + tj * 16 + m16;
                bh[tj] = *(const half8*)&bCh[col * BK + swq8];
                bl[tj] = *(const half8*)&bCl[col * BK + swq8];
            }

            // barrier1: every wave's frag reads complete -> buf[b] reusable
            if constexpr (ASYNC) {
                asm volatile("s_waitcnt lgkmcnt(0)" ::: "memory");
                __builtin_amdgcn_sched_barrier(0);
                __builtin_amdgcn_s_barrier();
            } else {
                __syncthreads();
            }

            // prefetch t+2 into the buffer we just finished reading
            if (t + 2 < NT) stage(t + 2);

            __builtin_amdgcn_s_setprio(1);
            #pragma unroll
            for (int tj = 0; tj < 4; ++tj) {
                #pragma unroll
                for (int ti = 0; ti < 4; ++ti) {
                    floatx4 a = acc[ti][tj];
                    a = __builtin_amdgcn_mfma_f32_16x16x32_f16(ah[ti], bh[tj], a, 0, 0, 0);
                    a = __builtin_amdgcn_mfma_f32_16x16x32_f16(ah[ti], bl[tj], a, 0, 0, 0);
                    a = __builtin_amdgcn_mfma_f32_16x16x32_f16(al[ti], bh[tj], a, 0, 0, 0);
                    acc[ti][tj] = a;
                }
            }
            __builtin_amdgcn_s_setprio(0);

            // barrier2: tile t+1 (issued during t-1) ready; counted wait --
            // the only outstanding loads are t+2's 8 GLLs (if issued).
            if constexpr (ASYNC) {
                if (t + 2 < NT) asm volatile("s_waitcnt vmcnt(8)" ::: "memory");
                else            asm volatile("s_waitcnt vmcnt(0)" ::: "memory");
                __builtin_amdgcn_s_barrier();
            } else {
                __syncthreads();
            }
        }

        // fused argmin epilogue. D layout: col=lane&15, row=quad*4+reg.
        // cols ascend (kt, then tj) per (ti,reg) + strict '<'  => first-occurrence.
        #pragma unroll
        for (int tj = 0; tj < 4; ++tj) {
            int col = k0 + wtj * 64 + tj * 16 + m16;
            float cv = c2s[col];
            #pragma unroll
            for (int ti = 0; ti < 4; ++ti)
                #pragma unroll
                for (int r = 0; r < 4; ++r) {
                    float s = x2s[wti * 64 + ti * 16 + q * 4 + r] + cv;
                    float v = s - 2.0f * acc[ti][tj][r];
                    if (v < bestV[ti][r]) { bestV[ti][r] = v; bestI[ti][r] = col; }
                }
        }
    }

    // cross-lane reduce over the 16 lanes sharing each row (lexicographic)
    #pragma unroll
    for (int ti = 0; ti < 4; ++ti)
        #pragma unroll
        for (int r = 0; r < 4; ++r) {
            float v = bestV[ti][r]; int ix = bestI[ti][r];
            #pragma unroll
            for (int off = 1; off < 16; off <<= 1) {
                float ov = __shfl_xor(v, off, 64);
                int   oi = __shfl_xor(ix, off, 64);
                if (ov < v || (ov == v && oi < ix)) { v = ov; ix = oi; }
            }
            bestV[ti][r] = v; bestI[ti][r] = ix;
        }

    __syncthreads();                   // tiles no longer needed; reuse as scratch
    float* rv  = (float*)sXh;          // [128][2]
    int*   rix = (int*)sCh;            // [128][2]
    if (m16 == 0) {
        #pragma unroll
        for (int ti = 0; ti < 4; ++ti)
            #pragma unroll
            for (int r = 0; r < 4; ++r) {
                int rloc = wti * 64 + ti * 16 + q * 4 + r;
                rv[rloc * 2 + wtj]  = bestV[ti][r];
                rix[rloc * 2 + wtj] = bestI[ti][r];
            }
    }
    __syncthreads();
    if (tid < BM) {
        float v0 = rv[tid * 2], v1 = rv[tid * 2 + 1];
        int   i0 = rix[tid * 2], i1 = rix[tid * 2 + 1];
        out[rowBase + tid] = (v1 < v0 || (v1 == v0 && i1 < i0)) ? i1 : i0;
    }
}

extern "C" void kernel_launch(void* const* d_in, const int* in_sizes, int n_in,
                              void* d_out, int out_size, void* d_ws, size_t ws_size,
                              hipStream_t stream) {
    const float* X = (const float*)d_in[0];   // [N, D]
    const float* C = (const float*)d_in[1];   // [K, D]
    int* out = (int*)d_out;

    char* ws = (char*)d_ws;
    const size_t c2_off  = 0;
    const size_t chi_off = (size_t)K_CL * 4;                       // 8 KB
    const size_t clo_off = chi_off + (size_t)K_CL * D_DIM * 2;     // +2 MB
    const size_t xhi_off = clo_off + (size_t)K_CL * D_DIM * 2;     // +2 MB
    const size_t xlo_off = xhi_off + (size_t)N_PTS * D_DIM * 2;    // +128 MB
    const size_t need_C    = xhi_off;                              // ~4.2 MB
    const size_t need_full = xlo_off + (size_t)N_PTS * D_DIM * 2;  // ~272.6 MB

    if (ws_size >= need_full) {
        float*    c2  = (float*)(ws + c2_off);
        _Float16* Chi = (_Float16*)(ws + chi_off);
        _Float16* Clo = (_Float16*)(ws + clo_off);
        _Float16* Xhi = (_Float16*)(ws + xhi_off);
        _Float16* Xlo = (_Float16*)(ws + xlo_off);
        row_norms_kernel<<<(K_CL * 64) / 256, 256, 0, stream>>>(C, c2, K_CL);
        conv_f16x2_kernel<<<(K_CL * D_DIM / 4) / 256, 256, 0, stream>>>(
            C, Chi, Clo, K_CL * D_DIM / 4);
        conv_f16x2_kernel<<<(N_PTS * D_DIM / 4 + 255) / 256, 256, 0, stream>>>(
            X, Xhi, Xlo, N_PTS * D_DIM / 4);
        kmeans_mfma<true, true><<<N_PTS / BM, 256, 0, stream>>>(
            X, C, Xhi, Xlo, Chi, Clo, c2, out);
    } else if (ws_size >= need_C) {
        float*    c2  = (float*)(ws + c2_off);
        _Float16* Chi = (_Float16*)(ws + chi_off);
        _Float16* Clo = (_Float16*)(ws + clo_off);
        row_norms_kernel<<<(K_CL * 64) / 256, 256, 0, stream>>>(C, c2, K_CL);
        conv_f16x2_kernel<<<(K_CL * D_DIM / 4) / 256, 256, 0, stream>>>(
            C, Chi, Clo, K_CL * D_DIM / 4);
        kmeans_mfma<false, true><<<N_PTS / BM, 256, 0, stream>>>(
            X, C, nullptr, nullptr, Chi, Clo, c2, out);
    } else {
        kmeans_mfma<false, false><<<N_PTS / BM, 256, 0, stream>>>(
            X, C, nullptr, nullptr, nullptr, nullptr, nullptr, out);
    }
}